// Round 1
// baseline (320.520 us; speedup 1.0000x reference)
//
#include <hip/hip_runtime.h>

#define NPTS 65536
#define IDIM 16
#define MI   1024
#define NSO  64   // S*OD = 8*8
#define LL   64

// ---------------- prep: transpose W, z^2, scaled prior weights ----------------
__global__ __launch_bounds__(256) void prep_kernel(
    const float* __restrict__ W,    // [64][1024]  (S,OD,M flattened)
    const float* __restrict__ z,    // [1024][16]
    const float* __restrict__ pw,   // [64][64]    (S,OD,L flattened)
    float* __restrict__ Wt,         // [1024][64]
    float* __restrict__ z2,         // [1024]
    float* __restrict__ pws)        // [64][64]
{
    int t = blockIdx.x * 256 + threadIdx.x;
    if (t < MI * NSO) {
        int m = t >> 6, so = t & 63;
        Wt[t] = W[so * MI + m];
    }
    int u = t - MI * NSO;
    if (u >= 0 && u < MI) {
        const float4* z4 = (const float4*)(z + (size_t)u * IDIM);
        float s = 0.f;
        #pragma unroll
        for (int q = 0; q < 4; q++) {
            float4 v = z4[q];
            s += v.x * v.x + v.y * v.y + v.z * v.z + v.w * v.w;
        }
        z2[u] = s;
    }
    int p = t - MI * NSO - MI;
    if (p >= 0 && p < NSO * LL) {
        pws[p] = 0.17677669529663687f * pw[p];   // sqrt(2/64)
    }
}

// ---------------- prior: random Fourier features ----------------
// 4 threads per point; each handles 2 of the 8 o-indices.
__global__ __launch_bounds__(256) void prior_kernel(
    const float* __restrict__ x,    // [N][16]
    const float* __restrict__ F,    // [8][16][64]
    const float* __restrict__ ph,   // [8][64]
    const float* __restrict__ pws,  // [64][64] scaled
    float* __restrict__ out)        // [64][N]
{
    int tid = threadIdx.x;
    int oq = tid >> 6;              // 0..3
    int nl = tid & 63;
    int n = blockIdx.x * 64 + nl;

    float xr[16];
    {
        const float4* x4 = (const float4*)(x + (size_t)n * IDIM);
        #pragma unroll
        for (int q = 0; q < 4; q++) {
            float4 v = x4[q];
            xr[4*q+0] = v.x; xr[4*q+1] = v.y; xr[4*q+2] = v.z; xr[4*q+3] = v.w;
        }
    }

    float po[2][8];                 // [osub][s]
    #pragma unroll
    for (int a = 0; a < 2; a++)
        #pragma unroll
        for (int s = 0; s < 8; s++) po[a][s] = 0.f;

    #pragma unroll
    for (int osub = 0; osub < 2; osub++) {
        int o = oq * 2 + osub;
        const float4* F4  = (const float4*)(F + (size_t)o * IDIM * LL);
        const float4* ph4 = (const float4*)(ph + (size_t)o * LL);
        for (int lq = 0; lq < 16; lq++) {
            float4 inner = ph4[lq];
            #pragma unroll
            for (int i = 0; i < 16; i++) {
                float4 fv = F4[i * 16 + lq];
                inner.x = fmaf(xr[i], fv.x, inner.x);
                inner.y = fmaf(xr[i], fv.y, inner.y);
                inner.z = fmaf(xr[i], fv.z, inner.z);
                inner.w = fmaf(xr[i], fv.w, inner.w);
            }
            float4 c;
            c.x = __cosf(inner.x); c.y = __cosf(inner.y);
            c.z = __cosf(inner.z); c.w = __cosf(inner.w);
            #pragma unroll
            for (int s = 0; s < 8; s++) {
                float4 pv = *(const float4*)(pws + (size_t)(s * 8 + o) * LL + lq * 4);
                po[osub][s] += c.x * pv.x + c.y * pv.y + c.z * pv.z + c.w * pv.w;
            }
        }
    }

    #pragma unroll
    for (int osub = 0; osub < 2; osub++) {
        int o = oq * 2 + osub;
        #pragma unroll
        for (int s = 0; s < 8; s++)
            out[(size_t)(s * 8 + o) * NPTS + n] = po[osub][s];
    }
}

// ---------------- data: fused RBF-kernel GEMM ----------------
// Block: 256 threads, tile = 128 n-rows x 64 so-cols, chunked over m (64/chunk).
__global__ __launch_bounds__(256) void data_kernel(
    const float* __restrict__ x,    // [N][16]
    const float* __restrict__ z,    // [1024][16]
    const float* __restrict__ Wt,   // [1024][64]
    const float* __restrict__ z2,   // [1024]
    float* __restrict__ out)        // [64][N], accumulate
{
    __shared__ __align__(16) float zc[64][16];
    __shared__            float z2c[64];
    __shared__ __align__(16) float wc[64][64];
    __shared__ __align__(16) float kt[64][128];

    int tid = threadIdx.x;
    int n0 = blockIdx.x * 128;

    // K-phase identity: one n-row per thread, half the m-chunk.
    int kn = tid & 127;
    int mh = tid >> 7;          // 0..1

    float xr[16], x2 = 0.f;
    {
        const float4* x4 = (const float4*)(x + (size_t)(n0 + kn) * IDIM);
        #pragma unroll
        for (int q = 0; q < 4; q++) {
            float4 v = x4[q];
            xr[4*q+0] = v.x; xr[4*q+1] = v.y; xr[4*q+2] = v.z; xr[4*q+3] = v.w;
            x2 += v.x * v.x + v.y * v.y + v.z * v.z + v.w * v.w;
        }
    }

    // GEMM identity: 8 so (contiguous, = fixed s block) x 4 n per thread.
    int og = tid >> 5;          // 0..7  -> so in [og*8, og*8+8)
    int tn = tid & 31;          // 0..31 -> n-local in [tn*4, tn*4+4)

    float acc[8][4];
    #pragma unroll
    for (int c = 0; c < 8; c++)
        #pragma unroll
        for (int j = 0; j < 4; j++) acc[c][j] = 0.f;

    for (int mc = 0; mc < 16; mc++) {
        int m0 = mc * 64;
        // ---- stage z, z2, Wt chunk ----
        {
            const float4* zg = (const float4*)(z + (size_t)m0 * IDIM);
            ((float4*)zc)[tid] = zg[tid];                       // 256 float4 = 64x16
            if (tid < 64) z2c[tid] = z2[m0 + tid];
            const float4* wg = (const float4*)(Wt + (size_t)m0 * NSO);
            float4* wl = (float4*)wc;
            #pragma unroll
            for (int k = 0; k < 4; k++)
                wl[tid + 256 * k] = wg[tid + 256 * k];          // 1024 float4 = 64x64
        }
        __syncthreads();

        // ---- K phase: 32 m per thread ----
        #pragma unroll 4
        for (int mm = 0; mm < 32; mm++) {
            int m = mh * 32 + mm;
            const float4* zr = (const float4*)zc[m];
            float4 za = zr[0], zb = zr[1], zg2 = zr[2], zd = zr[3];
            float dot = 0.f;
            dot = fmaf(xr[0],  za.x, dot); dot = fmaf(xr[1],  za.y, dot);
            dot = fmaf(xr[2],  za.z, dot); dot = fmaf(xr[3],  za.w, dot);
            dot = fmaf(xr[4],  zb.x, dot); dot = fmaf(xr[5],  zb.y, dot);
            dot = fmaf(xr[6],  zb.z, dot); dot = fmaf(xr[7],  zb.w, dot);
            dot = fmaf(xr[8],  zg2.x, dot); dot = fmaf(xr[9],  zg2.y, dot);
            dot = fmaf(xr[10], zg2.z, dot); dot = fmaf(xr[11], zg2.w, dot);
            dot = fmaf(xr[12], zd.x, dot); dot = fmaf(xr[13], zd.y, dot);
            dot = fmaf(xr[14], zd.z, dot); dot = fmaf(xr[15], zd.w, dot);
            float dist = fmaxf(x2 + z2c[m] - 2.f * dot, 0.f);
            kt[m][kn] = __expf(-0.5f * dist);
        }
        __syncthreads();

        // ---- GEMM phase: outer product over chunk ----
        #pragma unroll 4
        for (int m = 0; m < 64; m++) {
            float4 k4 = *(const float4*)&kt[m][tn * 4];
            float4 w0 = *(const float4*)&wc[m][og * 8];
            float4 w1 = *(const float4*)&wc[m][og * 8 + 4];
            float kk[4] = {k4.x, k4.y, k4.z, k4.w};
            float ww[8] = {w0.x, w0.y, w0.z, w0.w, w1.x, w1.y, w1.z, w1.w};
            #pragma unroll
            for (int c = 0; c < 8; c++)
                #pragma unroll
                for (int j = 0; j < 4; j++)
                    acc[c][j] = fmaf(ww[c], kk[j], acc[c][j]);
        }
        __syncthreads();
    }

    // ---- epilogue: add onto prior already in out ----
    #pragma unroll
    for (int c = 0; c < 8; c++) {
        float4* op = (float4*)(out + (size_t)(og * 8 + c) * NPTS + n0 + tn * 4);
        float4 v = *op;
        v.x += acc[c][0]; v.y += acc[c][1]; v.z += acc[c][2]; v.w += acc[c][3];
        *op = v;
    }
}

extern "C" void kernel_launch(void* const* d_in, const int* in_sizes, int n_in,
                              void* d_out, int out_size, void* d_ws, size_t ws_size,
                              hipStream_t stream) {
    const float* x  = (const float*)d_in[0];   // [65536][16]
    const float* z  = (const float*)d_in[1];   // [1024][16]
    const float* W  = (const float*)d_in[2];   // [8][8][1024]
    const float* F  = (const float*)d_in[3];   // [8][16][64]
    const float* ph = (const float*)d_in[4];   // [8][64]
    const float* pw = (const float*)d_in[5];   // [8][8][64]
    float* out = (float*)d_out;

    float* Wt  = (float*)d_ws;                 // 65536 floats
    float* z2  = Wt + MI * NSO;                // 1024 floats
    float* pws = z2 + MI;                      // 4096 floats

    prep_kernel<<<276, 256, 0, stream>>>(W, z, pw, Wt, z2, pws);
    prior_kernel<<<1024, 256, 0, stream>>>(x, F, ph, pws, out);
    data_kernel<<<512, 256, 0, stream>>>(x, z, Wt, z2, out);
}

// Round 2
// 131.299 us; speedup vs baseline: 2.4411x; 2.4411x over previous
//
#include <hip/hip_runtime.h>
#include <hip/hip_bf16.h>

#define N_PTS 65536

typedef __attribute__((ext_vector_type(8))) short short8;
typedef __attribute__((ext_vector_type(4))) short short4v;
typedef __attribute__((ext_vector_type(4))) float float4v;

__device__ __forceinline__ short f2b(float f) {
    __hip_bfloat16 h = __float2bfloat16(f);
    return *(short*)&h;
}
__device__ __forceinline__ float b2f(short s) {
    __hip_bfloat16 h = *(__hip_bfloat16*)&s;
    return __bfloat162float(h);
}

// ---------------- prep: bf16 casts + transposes + block-diag weight matrix ----------------
// ws layout (bytes):
//   zb   [1024][16] bf16   @ 0        (32768)
//   FbB  [8][64][16] bf16  @ 32768    (16384)   FbB[o][l][i] = F[o][i][l]
//   BWd  [64][512] bf16    @ 49152    (65536)   BWd[so][o*64+l] = (so%8==o) ? sqrt(2/64)*pw[so][l] : 0
//   Wtb  [64][1024] bf16   @ 114688   (131072)  bf16(W)
//   z2   [1024] f32        @ 245760   (4096)    ||bf16(z_m)||^2
__global__ __launch_bounds__(256) void prep_kernel(
    const float* __restrict__ z, const float* __restrict__ W,
    const float* __restrict__ F, const float* __restrict__ pw,
    short* __restrict__ zb, short* __restrict__ FbB,
    short* __restrict__ BWd, short* __restrict__ Wtb,
    float* __restrict__ z2)
{
    int t = blockIdx.x * 256 + threadIdx.x;
    if (t < 1024) {
        float s = 0.f;
        #pragma unroll
        for (int i = 0; i < 16; i++) {
            short b = f2b(z[t * 16 + i]);
            zb[t * 16 + i] = b;
            float v = b2f(b);
            s += v * v;
        }
        z2[t] = s;
    } else if (t < 9216) {
        int p = t - 1024;
        int o = p >> 10, l = (p >> 4) & 63, i = p & 15;
        FbB[p] = f2b(F[o * 1024 + i * 64 + l]);
    } else if (t < 41984) {
        int p = t - 9216;
        int so = p >> 9, ol = p & 511, o = ol >> 6, l = ol & 63;
        float v = ((so & 7) == o) ? 0.17677669529663687f * pw[so * 64 + l] : 0.f;
        BWd[p] = f2b(v);
    } else if (t < 107520) {
        int p = t - 41984;
        Wtb[p] = f2b(W[p]);
    }
}

// ---------------- fused prior + data, all-MFMA ----------------
// Block: 256 thr (4 waves), n-block = 64. Wave w owns so-strip [16w,16w+16) for
// the output accumulator and n-tile w for basis/K production.
// MFMA 16x16x32 bf16 layouts (guide §3, m89/m120-verified):
//   A: lane(q=l>>4,c=l&15) elem j -> A[row=c][k=q*8+j]
//   B: elem j -> B[k=q*8+j][col=c]
//   D: reg r -> D[row=q*4+r][col=c]
__global__ __launch_bounds__(256, 4) void fused_kernel(
    const float* __restrict__ x, const float* __restrict__ ph,
    const short* __restrict__ zb, const short* __restrict__ FbB,
    const short* __restrict__ BWd, const short* __restrict__ Wtb,
    const float* __restrict__ z2, float* __restrict__ out)
{
    // 64 rows x 68 bf16: stride 136 B (8-B aligned for b64 reads, dword-step 34
    // -> 2-way bank aliasing only = free)
    __shared__ __align__(16) short tileL[64 * 68];
    __shared__ float x2c[64];

    const int tid = threadIdx.x;
    const int lane = tid & 63, w = tid >> 6;
    const int q = lane >> 4, c = lane & 15;
    const int n0 = blockIdx.x * 64;

    // ---- stage ||bf16(x_n)||^2 for the block's 64 rows ----
    if (tid < 64) {
        float s = 0.f;
        const float4v* xr = (const float4v*)(x + (size_t)(n0 + tid) * 16);
        #pragma unroll
        for (int k = 0; k < 4; k++) {
            float4v v = xr[k];
            float a0 = b2f(f2b(v.x)), a1 = b2f(f2b(v.y));
            float a2 = b2f(f2b(v.z)), a3 = b2f(f2b(v.w));
            s += a0 * a0 + a1 * a1 + a2 * a2 + a3 * a3;
        }
        x2c[tid] = s;
    }

    // ---- x A-fragment (K=16 real, quads 2,3 zero-padded) ----
    short8 ax = (short8)0;
    if (q < 2) {
        const float4v* xp = (const float4v*)(x + (size_t)(n0 + 16 * w + c) * 16 + q * 8);
        float4v v0 = xp[0], v1 = xp[1];
        ax[0] = f2b(v0.x); ax[1] = f2b(v0.y); ax[2] = f2b(v0.z); ax[3] = f2b(v0.w);
        ax[4] = f2b(v1.x); ax[5] = f2b(v1.y); ax[6] = f2b(v1.z); ax[7] = f2b(v1.w);
    }

    float4v acc[4];
    #pragma unroll
    for (int i = 0; i < 4; i++) acc[i] = (float4v)(0.f);

    __syncthreads();

    float x2r[4];
    #pragma unroll
    for (int r = 0; r < 4; r++) x2r[r] = x2c[16 * w + q * 4 + r];

    // ================= prior: cos(x.F + ph) @ blockdiag(pws) =================
    for (int o = 0; o < 8; o++) {
        // wave w produces basis rows [16w, 16w+16) x 64 l into tileL
        #pragma unroll
        for (int lt = 0; lt < 4; lt++) {
            short8 bf = (short8)0;
            if (q < 2) bf = *(const short8*)(FbB + ((o * 64 + lt * 16 + c) * 16 + q * 8));
            float4v d = __builtin_amdgcn_mfma_f32_16x16x32_bf16(ax, bf, (float4v)(0.f), 0, 0, 0);
            float phv = ph[o * 64 + lt * 16 + c];
            #pragma unroll
            for (int r = 0; r < 4; r++) {
                float cv = __cosf(d[r] + phv);
                tileL[(16 * w + q * 4 + r) * 68 + lt * 16 + c] = f2b(cv);
            }
        }
        __syncthreads();
        // GEMM2: acc[so-strip w][all 64 n] += BWd[:, o*64..o*64+64] x basis^T
        #pragma unroll
        for (int ks = 0; ks < 2; ks++) {
            short8 aw = *(const short8*)(BWd + ((16 * w + c) * 512 + o * 64 + ks * 32 + q * 8));
            #pragma unroll
            for (int nt = 0; nt < 4; nt++) {
                const short* tp = tileL + (nt * 16 + c) * 68 + ks * 32 + q * 8;
                short4v lo = *(const short4v*)tp;
                short4v hi = *(const short4v*)(tp + 4);
                short8 bb;
                bb[0] = lo[0]; bb[1] = lo[1]; bb[2] = lo[2]; bb[3] = lo[3];
                bb[4] = hi[0]; bb[5] = hi[1]; bb[6] = hi[2]; bb[7] = hi[3];
                acc[nt] = __builtin_amdgcn_mfma_f32_16x16x32_bf16(aw, bb, acc[nt], 0, 0, 0);
            }
        }
        __syncthreads();
    }

    // ================= data: exp(-.5||x-z||^2) @ W^T =================
    for (int mc = 0; mc < 16; mc++) {
        int m0 = mc * 64;
        // wave w produces K rows [16w,16w+16) x 64 m into tileL
        #pragma unroll
        for (int mt = 0; mt < 4; mt++) {
            short8 bz = (short8)0;
            if (q < 2) bz = *(const short8*)(zb + ((m0 + mt * 16 + c) * 16 + q * 8));
            float4v d = __builtin_amdgcn_mfma_f32_16x16x32_bf16(ax, bz, (float4v)(0.f), 0, 0, 0);
            float z2v = z2[m0 + mt * 16 + c];
            #pragma unroll
            for (int r = 0; r < 4; r++) {
                float dist = fmaxf(x2r[r] + z2v - 2.f * d[r], 0.f);
                float e = __expf(-0.5f * dist);
                tileL[(16 * w + q * 4 + r) * 68 + mt * 16 + c] = f2b(e);
            }
        }
        __syncthreads();
        #pragma unroll
        for (int ks = 0; ks < 2; ks++) {
            short8 aw = *(const short8*)(Wtb + ((16 * w + c) * 1024 + m0 + ks * 32 + q * 8));
            #pragma unroll
            for (int nt = 0; nt < 4; nt++) {
                const short* tp = tileL + (nt * 16 + c) * 68 + ks * 32 + q * 8;
                short4v lo = *(const short4v*)tp;
                short4v hi = *(const short4v*)(tp + 4);
                short8 bb;
                bb[0] = lo[0]; bb[1] = lo[1]; bb[2] = lo[2]; bb[3] = lo[3];
                bb[4] = hi[0]; bb[5] = hi[1]; bb[6] = hi[2]; bb[7] = hi[3];
                acc[nt] = __builtin_amdgcn_mfma_f32_16x16x32_bf16(aw, bb, acc[nt], 0, 0, 0);
            }
        }
        __syncthreads();
    }

    // ---- epilogue: D[row=q*4+r -> so=16w+..][col=c -> n] ----
    #pragma unroll
    for (int nt = 0; nt < 4; nt++) {
        #pragma unroll
        for (int r = 0; r < 4; r++) {
            out[(size_t)(16 * w + q * 4 + r) * N_PTS + n0 + nt * 16 + c] = acc[nt][r];
        }
    }
}

extern "C" void kernel_launch(void* const* d_in, const int* in_sizes, int n_in,
                              void* d_out, int out_size, void* d_ws, size_t ws_size,
                              hipStream_t stream) {
    const float* x  = (const float*)d_in[0];   // [65536][16]
    const float* z  = (const float*)d_in[1];   // [1024][16]
    const float* W  = (const float*)d_in[2];   // [8][8][1024] = [64][1024]
    const float* F  = (const float*)d_in[3];   // [8][16][64]
    const float* ph = (const float*)d_in[4];   // [8][64]
    const float* pw = (const float*)d_in[5];   // [8][8][64] = [64][64]
    float* out = (float*)d_out;                // [64][65536]

    char* ws = (char*)d_ws;
    short* zb  = (short*)(ws);            // 32768 B
    short* FbB = (short*)(ws + 32768);    // 16384 B
    short* BWd = (short*)(ws + 49152);    // 65536 B
    short* Wtb = (short*)(ws + 114688);   // 131072 B
    float* z2  = (float*)(ws + 245760);   // 4096 B

    prep_kernel<<<420, 256, 0, stream>>>(z, W, F, pw, zb, FbB, BWd, Wtb, z2);
    fused_kernel<<<1024, 256, 0, stream>>>(x, ph, zb, FbB, BWd, Wtb, z2, out);
}

// Round 3
// 122.796 us; speedup vs baseline: 2.6102x; 1.0692x over previous
//
#include <hip/hip_runtime.h>
#include <hip/hip_bf16.h>

#define N_PTS 65536
#define LOG2E 1.4426950408889634f

typedef __attribute__((ext_vector_type(8))) short short8;
typedef __attribute__((ext_vector_type(4))) float float4v;

#if __has_builtin(__builtin_amdgcn_exp2f)
#define EXP2F(x) __builtin_amdgcn_exp2f(x)
#else
#define EXP2F(x) exp2f(x)
#endif

__device__ __forceinline__ short f2b(float f) {
    __hip_bfloat16 h = __float2bfloat16(f);
    return *(short*)&h;
}
__device__ __forceinline__ float b2f(short s) {
    __hip_bfloat16 h = *(__hip_bfloat16*)&s;
    return __bfloat162float(h);
}

// ---------------- prep ----------------
// ws layout (bytes), unchanged offsets from R2:
//   zb   [1024][16] bf16  @ 0        bf16(log2e * z)
//   FbB  [8][64][16] bf16 @ 32768    FbB[o][l][i] = bf16(F[o][i][l])
//   BWd  [64][512] bf16   @ 49152    block-diag sqrt(2/64)*pw
//   Wtb  [64][1024] bf16  @ 114688   bf16(W)
//   z2h  [1024] f32       @ 245760   0.5*log2e*||bf16(z_m)||^2
__global__ __launch_bounds__(256) void prep_kernel(
    const float* __restrict__ z, const float* __restrict__ W,
    const float* __restrict__ F, const float* __restrict__ pw,
    short* __restrict__ zb, short* __restrict__ FbB,
    short* __restrict__ BWd, short* __restrict__ Wtb,
    float* __restrict__ z2h)
{
    int t = blockIdx.x * 256 + threadIdx.x;
    if (t < 16384) {
        zb[t] = f2b(LOG2E * z[t]);                       // coalesced cast
    } else if (t < 17408) {
        int m = t - 16384;
        const float4v* zp = (const float4v*)(z + (size_t)m * 16);
        float s = 0.f;
        #pragma unroll
        for (int k = 0; k < 4; k++) {
            float4v v = zp[k];
            float a0 = b2f(f2b(v.x)), a1 = b2f(f2b(v.y));
            float a2 = b2f(f2b(v.z)), a3 = b2f(f2b(v.w));
            s += a0 * a0 + a1 * a1 + a2 * a2 + a3 * a3;
        }
        z2h[m] = 0.5f * LOG2E * s;
    } else if (t < 25600) {
        int p = t - 17408;
        int o = p >> 10, l = (p >> 4) & 63, i = p & 15;
        FbB[p] = f2b(F[o * 1024 + i * 64 + l]);
    } else if (t < 58368) {
        int p = t - 25600;
        int so = p >> 9, ol = p & 511, o = ol >> 6;
        float v = ((so & 7) == o) ? 0.17677669529663687f * pw[so * 64 + (ol & 63)] : 0.f;
        BWd[p] = f2b(v);
    } else if (t < 123904) {
        int p = t - 58368;
        Wtb[p] = f2b(W[p]);
    }
}

// ---------------- fused prior + data ----------------
// 256 thr (4 waves), n-block 64. 128-wide chunks, double-buffered tile,
// ONE barrier per chunk. MFMA C-operand carries phase / -(x2+z2) terms.
// tile stride 136 shorts = 272 B (16B-aligned rows; dword-stride 68 -> 2-way
// bank aliasing only = free).
__global__ __launch_bounds__(256, 4) void fused_kernel(
    const float* __restrict__ x, const float* __restrict__ ph,
    const short* __restrict__ zb, const short* __restrict__ FbB,
    const short* __restrict__ BWd, const short* __restrict__ Wtb,
    const float* __restrict__ z2h, float* __restrict__ out)
{
    __shared__ __align__(16) short tile[2][64 * 136];
    __shared__ float phc[512];
    __shared__ float x2c[64];

    const int tid = threadIdx.x;
    const int lane = tid & 63, w = tid >> 6;
    const int q = lane >> 4, c = lane & 15;
    const int n0 = blockIdx.x * 64;

    // stage phases + scaled ||x||^2
    for (int i = tid; i < 512; i += 256) phc[i] = ph[i];
    if (tid < 64) {
        float s = 0.f;
        const float4v* xr = (const float4v*)(x + (size_t)(n0 + tid) * 16);
        #pragma unroll
        for (int k = 0; k < 4; k++) {
            float4v v = xr[k];
            float a0 = b2f(f2b(v.x)), a1 = b2f(f2b(v.y));
            float a2 = b2f(f2b(v.z)), a3 = b2f(f2b(v.w));
            s += a0 * a0 + a1 * a1 + a2 * a2 + a3 * a3;
        }
        x2c[tid] = 0.5f * LOG2E * s;
    }

    // x A-fragment (K=16 real, quads 2,3 zero)
    short8 ax = (short8)0;
    if (q < 2) {
        const float4v* xp = (const float4v*)(x + (size_t)(n0 + 16 * w + c) * 16 + q * 8);
        float4v v0 = xp[0], v1 = xp[1];
        ax[0] = f2b(v0.x); ax[1] = f2b(v0.y); ax[2] = f2b(v0.z); ax[3] = f2b(v0.w);
        ax[4] = f2b(v1.x); ax[5] = f2b(v1.y); ax[6] = f2b(v1.z); ax[7] = f2b(v1.w);
    }

    float4v acc[4];
    #pragma unroll
    for (int i = 0; i < 4; i++) acc[i] = (float4v)(0.f);

    __syncthreads();

    // ============ prior: cos(x.F + ph) @ blockdiag(pws), 4 chunks of 128 l ============
    #pragma unroll
    for (int p = 0; p < 4; p++) {
        short* tl = tile[p & 1];
        #pragma unroll
        for (int lt = 0; lt < 8; lt++) {
            short8 bf = (short8)0;
            if (q < 2) bf = *(const short8*)(FbB + ((p * 128 + lt * 16 + c) * 16 + q * 8));
            float phv = phc[p * 128 + lt * 16 + c];
            float4v c0 = {phv, phv, phv, phv};
            float4v d = __builtin_amdgcn_mfma_f32_16x16x32_bf16(ax, bf, c0, 0, 0, 0);
            #pragma unroll
            for (int r = 0; r < 4; r++)
                tl[(16 * w + q * 4 + r) * 136 + lt * 16 + c] = f2b(__cosf(d[r]));
        }
        // prefetch A-fragments (L2) into the barrier shadow
        short8 aw[4];
        #pragma unroll
        for (int ks = 0; ks < 4; ks++)
            aw[ks] = *(const short8*)(BWd + ((16 * w + c) * 512 + p * 128 + ks * 32 + q * 8));
        __syncthreads();
        #pragma unroll
        for (int ks = 0; ks < 4; ks++) {
            #pragma unroll
            for (int nt = 0; nt < 4; nt++) {
                short8 bb = *(const short8*)(tl + (nt * 16 + c) * 136 + ks * 32 + q * 8);
                acc[nt] = __builtin_amdgcn_mfma_f32_16x16x32_bf16(aw[ks], bb, acc[nt], 0, 0, 0);
            }
        }
    }

    float mx2[4];
    #pragma unroll
    for (int r = 0; r < 4; r++) mx2[r] = -x2c[16 * w + q * 4 + r];

    // ============ data: exp2(log2e*(dot - (x2+z2)/2)) @ W^T, 8 chunks of 128 m ============
    #pragma unroll
    for (int mc = 0; mc < 8; mc++) {
        short* tl = tile[mc & 1];
        int m0 = mc * 128;
        #pragma unroll
        for (int mt = 0; mt < 8; mt++) {
            short8 bz = (short8)0;
            if (q < 2) bz = *(const short8*)(zb + ((m0 + mt * 16 + c) * 16 + q * 8));
            float z2v = z2h[m0 + mt * 16 + c];
            float4v c0;
            #pragma unroll
            for (int r = 0; r < 4; r++) c0[r] = mx2[r] - z2v;
            float4v d = __builtin_amdgcn_mfma_f32_16x16x32_bf16(ax, bz, c0, 0, 0, 0);
            #pragma unroll
            for (int r = 0; r < 4; r++)
                tl[(16 * w + q * 4 + r) * 136 + mt * 16 + c] = f2b(EXP2F(d[r]));
        }
        short8 aw[4];
        #pragma unroll
        for (int ks = 0; ks < 4; ks++)
            aw[ks] = *(const short8*)(Wtb + ((16 * w + c) * 1024 + m0 + ks * 32 + q * 8));
        __syncthreads();
        #pragma unroll
        for (int ks = 0; ks < 4; ks++) {
            #pragma unroll
            for (int nt = 0; nt < 4; nt++) {
                short8 bb = *(const short8*)(tl + (nt * 16 + c) * 136 + ks * 32 + q * 8);
                acc[nt] = __builtin_amdgcn_mfma_f32_16x16x32_bf16(aw[ks], bb, acc[nt], 0, 0, 0);
            }
        }
    }

    // epilogue: D[row=q*4+r -> so=16w+..][col=c -> n]
    #pragma unroll
    for (int nt = 0; nt < 4; nt++) {
        #pragma unroll
        for (int r = 0; r < 4; r++) {
            out[(size_t)(16 * w + q * 4 + r) * N_PTS + n0 + nt * 16 + c] = acc[nt][r];
        }
    }
}

extern "C" void kernel_launch(void* const* d_in, const int* in_sizes, int n_in,
                              void* d_out, int out_size, void* d_ws, size_t ws_size,
                              hipStream_t stream) {
    const float* x  = (const float*)d_in[0];   // [65536][16]
    const float* z  = (const float*)d_in[1];   // [1024][16]
    const float* W  = (const float*)d_in[2];   // [8][8][1024] = [64][1024]
    const float* F  = (const float*)d_in[3];   // [8][16][64]
    const float* ph = (const float*)d_in[4];   // [8][64]
    const float* pw = (const float*)d_in[5];   // [8][8][64] = [64][64]
    float* out = (float*)d_out;                // [64][65536]

    char* ws = (char*)d_ws;
    short* zb  = (short*)(ws);            // 32768 B
    short* FbB = (short*)(ws + 32768);    // 16384 B
    short* BWd = (short*)(ws + 49152);    // 65536 B
    short* Wtb = (short*)(ws + 114688);   // 131072 B
    float* z2h = (float*)(ws + 245760);   // 4096 B

    prep_kernel<<<484, 256, 0, stream>>>(z, W, F, pw, zb, FbB, BWd, Wtb, z2h);
    fused_kernel<<<1024, 256, 0, stream>>>(x, ph, zb, FbB, BWd, Wtb, z2h, out);
}